// Round 1
// baseline (319.185 us; speedup 1.0000x reference)
//
#include <hip/hip_runtime.h>
#include <hip/hip_bf16.h>

#define NQ 8
#define DIM 256
#define NB 16
#define NW 16
#define VOCABN 50257
#define EMBN 512

// ---------- wave64 helpers ----------
__device__ __forceinline__ float2 shfl2(float2 a, int m){
  float2 r; r.x = __shfl_xor(a.x, m, 64); r.y = __shfl_xor(a.y, m, 64); return r;
}
__device__ __forceinline__ float wave_sum(float x){
  #pragma unroll
  for (int off = 1; off < 64; off <<= 1) x += __shfl_xor(x, off, 64);
  return x;
}

// RY pair update: a0' = c a0 - s a1 ; a1' = s a0 + c a1  (real matrix)
__device__ __forceinline__ void ry_pair(float2& a0, float2& a1, float c, float s){
  float2 n0 = make_float2(c*a0.x - s*a1.x, c*a0.y - s*a1.y);
  float2 n1 = make_float2(s*a0.x + c*a1.x, s*a0.y + c*a1.y);
  a0 = n0; a1 = n1;
}
// RX pair update: a0' = c a0 - i s a1 ; a1' = -i s a0 + c a1
__device__ __forceinline__ void rx_pair(float2& a0, float2& a1, float c, float s){
  float2 n0 = make_float2(c*a0.x + s*a1.y, c*a0.y - s*a1.x);
  float2 n1 = make_float2(c*a1.x + s*a0.y, c*a1.y - s*a0.x);
  a0 = n0; a1 = n1;
}

// State layout: thread(lane) holds amplitudes idx = (r<<6)|lane, r=0..3.
// idx bit k: k<6 -> lane bit, k=6 -> r bit0, k=7 -> r bit1. Qubit q <-> bit (7-q).
__device__ __forceinline__ void apply_gate(float2 v[4], int lane, int kind, int cbit, int tbit,
                                           float c, float s){
  if (kind == 0){ // RY on bit tbit
    if (tbit == 7){ ry_pair(v[0], v[2], c, s); ry_pair(v[1], v[3], c, s); }
    else if (tbit == 6){ ry_pair(v[0], v[1], c, s); ry_pair(v[2], v[3], c, s); }
    else {
      int m = 1 << tbit;
      #pragma unroll
      for (int r = 0; r < 4; ++r){
        float2 w = shfl2(v[r], m);
        float sg = (lane & m) ? s : -s;
        v[r] = make_float2(c*v[r].x + sg*w.x, c*v[r].y + sg*w.y);
      }
    }
  } else { // CRX: control bit cbit, target bit tbit
    if (tbit >= 6){
      if (cbit >= 6){
        // both in registers
        if (cbit == 7) rx_pair(v[2], v[3], c, s);   // cbit7 set -> r in {2,3}; tbit6 pair
        else           rx_pair(v[1], v[3], c, s);   // cbit6 set -> r in {1,3}; tbit7 pair
      } else {
        int cm = 1 << cbit;
        if (lane & cm){
          if (tbit == 7){ rx_pair(v[0], v[2], c, s); rx_pair(v[1], v[3], c, s); }
          else          { rx_pair(v[0], v[1], c, s); rx_pair(v[2], v[3], c, s); }
        }
      }
    } else {
      int m = 1 << tbit;
      if (cbit >= 6){
        // register control, lane target. RX cross-lane update is role-symmetric:
        // v' = (c vx + s wy, c vy - s wx)
        int r0 = (cbit == 6) ? 1 : 2;
        float2 w0 = shfl2(v[r0], m);
        float2 w1 = shfl2(v[3], m);
        v[r0] = make_float2(c*v[r0].x + s*w0.y, c*v[r0].y - s*w0.x);
        v[3]  = make_float2(c*v[3].x  + s*w1.y, c*v[3].y  - s*w1.x);
      } else {
        int cm = 1 << cbit;
        bool act = (lane & cm) != 0;
        #pragma unroll
        for (int r = 0; r < 4; ++r){
          float2 w = shfl2(v[r], m);
          if (act) v[r] = make_float2(c*v[r].x + s*w.y, c*v[r].y - s*w.x);
        }
      }
    }
  }
}

// One sim14 layer = 32 gates. cs[g] = (cos(th/2), sin(th/2)).
__device__ __forceinline__ void sim32(float2 v[4], int lane, const float2* __restrict__ cs){
  // gate tables in bit-space (bit = 7 - qubit)
  constexpr int KIND[32] = {0,0,0,0,0,0,0,0, 1,1,1,1,1,1,1,1, 0,0,0,0,0,0,0,0, 1,1,1,1,1,1,1,1};
  constexpr int CB[32]   = {0,0,0,0,0,0,0,0, 0,1,2,3,4,5,6,7, 0,0,0,0,0,0,0,0, 0,7,6,5,4,3,2,1};
  constexpr int TB[32]   = {7,6,5,4,3,2,1,0, 7,0,1,2,3,4,5,6, 7,6,5,4,3,2,1,0, 1,0,7,6,5,4,3,2};
  #pragma unroll
  for (int g = 0; g < 32; ++g){
    float2 p = cs[g];
    apply_gate(v, lane, KIND[g], CB[g], TB[g], p.x, p.y);
  }
}

__device__ __forceinline__ void measure_xyz(const float2 v[4], int lane, float* exps){
  #pragma unroll
  for (int q = 0; q < 8; ++q){
    const int t = 7 - q;
    float xr = 0.f, xi = 0.f, zz = 0.f;
    if (t == 7){
      #pragma unroll
      for (int r = 0; r < 2; ++r){
        float2 a0 = v[r], a1 = v[r+2];
        xr += a0.x*a1.x + a0.y*a1.y;
        xi += a0.x*a1.y - a0.y*a1.x;
        zz += (a0.x*a0.x + a0.y*a0.y) - (a1.x*a1.x + a1.y*a1.y);
      }
    } else if (t == 6){
      #pragma unroll
      for (int r = 0; r < 4; r += 2){
        float2 a0 = v[r], a1 = v[r+1];
        xr += a0.x*a1.x + a0.y*a1.y;
        xi += a0.x*a1.y - a0.y*a1.x;
        zz += (a0.x*a0.x + a0.y*a0.y) - (a1.x*a1.x + a1.y*a1.y);
      }
    } else {
      int m = 1 << t;
      #pragma unroll
      for (int r = 0; r < 4; ++r){
        float2 a = v[r];
        float2 w = shfl2(a, m);
        if (!(lane & m)){
          xr += a.x*w.x + a.y*w.y;
          xi += a.x*w.y - a.y*w.x;
          zz += (a.x*a.x + a.y*a.y) - (w.x*w.x + w.y*w.y);
        }
      }
    }
    xr = wave_sum(xr); xi = wave_sum(xi); zz = wave_sum(zz);
    if (lane == 0){ exps[q] = 2.f*xr; exps[8+q] = 2.f*xi; exps[16+q] = zz; }
  }
}

// ---------- K1: embeddings -> rotation angles -> (cos,sin); coeffs; qff (cos,sin) ----------
__global__ __launch_bounds__(64) void k_prep(
    const int* __restrict__ x, const float* __restrict__ embW,
    const float* __restrict__ e2rW, const float* __restrict__ e2rb,
    const float* __restrict__ mixri, const float* __restrict__ qff,
    float* __restrict__ wcs, float* __restrict__ coeffs, float* __restrict__ qcs)
{
  const int p = blockIdx.x;    // 0..255 = b*16+w
  const int j = threadIdx.x;   // 0..63 rotation index
  const int tok = x[p];
  const float4* er = (const float4*)(embW + (size_t)tok * EMBN);
  const float4* wr = (const float4*)(e2rW + (size_t)j * EMBN);
  float acc = e2rb[j];
  #pragma unroll 4
  for (int k = 0; k < EMBN/4; ++k){
    float4 e = er[k], w4 = wr[k];
    acc += e.x*w4.x + e.y*w4.y + e.z*w4.z + e.w*w4.w;
  }
  float th = 0.5f * acc;
  wcs[(p*64 + j)*2 + 0] = cosf(th);
  wcs[(p*64 + j)*2 + 1] = sinf(th);
  if (p == 0){
    if (j < 32){ float t = 0.5f * qff[j]; qcs[2*j] = cosf(t); qcs[2*j+1] = sinf(t); }
    if (j < 16){
      float ssum = 0.f;
      for (int i = 0; i < 16; ++i){
        float mr = mixri[2*i], mi = mixri[2*i+1];
        ssum += sqrtf(mr*mr + mi*mi);
      }
      ssum = fmaxf(ssum, 1e-12f);
      coeffs[2*j]   = mixri[2*j]   / ssum;
      coeffs[2*j+1] = mixri[2*j+1] / ssum;
    }
  }
}

// ---------- K2: full quantum pipeline, one block per batch element ----------
__global__ __launch_bounds__(1024) void k_sim(
    const float* __restrict__ wcs, const float* __restrict__ coeffs,
    const float* __restrict__ qcs, const float* __restrict__ poly,
    const float* __restrict__ ff1W, const float* __restrict__ ff1b,
    float* __restrict__ hT, float* __restrict__ fprobs)
{
  const int b = blockIdx.x;
  const int tid = threadIdx.x;
  const int w = tid >> 6;
  const int lane = tid & 63;

  __shared__ float2 stall[NW][DIM];
  __shared__ float2 partial[4][DIM];
  __shared__ float2 work[DIM];
  __shared__ float2 accs[DIM];
  __shared__ float exps[24];

  if (tid < DIM){
    float p0 = poly[0];
    float one = (tid == 0) ? 1.f : 0.f;
    work[tid] = make_float2(one, 0.f);
    accs[tid] = make_float2(p0*one, 0.f);
  }
  __syncthreads();

  const float2 coef = make_float2(coeffs[2*w], coeffs[2*w+1]);
  const float2* mycs = ((const float2*)wcs) + (b*NW + w)*64;

  for (int d = 1; d <= 3; ++d){
    float2 v[4];
    #pragma unroll
    for (int r = 0; r < 4; ++r) v[r] = work[(r<<6) | lane];
    for (int l = 0; l < 2; ++l) sim32(v, lane, mycs + 32*l);
    // stage coeff-scaled state
    #pragma unroll
    for (int r = 0; r < 4; ++r){
      float2 a = v[r];
      stall[w][(r<<6) | lane] = make_float2(coef.x*a.x - coef.y*a.y, coef.x*a.y + coef.y*a.x);
    }
    __syncthreads();
    { // reduce over the 16 words: 1024 threads = 4 groups x 256 idx
      int idx = tid & 255, grp = tid >> 8;
      float2 s = make_float2(0.f, 0.f);
      #pragma unroll
      for (int ww = 0; ww < 4; ++ww){
        float2 a = stall[grp*4 + ww][idx];
        s.x += a.x; s.y += a.y;
      }
      partial[grp][idx] = s;
    }
    __syncthreads();
    if (tid < DIM){
      float2 s = make_float2(0.f, 0.f);
      #pragma unroll
      for (int g2 = 0; g2 < 4; ++g2){ s.x += partial[g2][tid].x; s.y += partial[g2][tid].y; }
      float pd = poly[d];
      work[tid] = s;
      accs[tid].x += pd*s.x; accs[tid].y += pd*s.y;
    }
    __syncthreads();
  }

  const float psum = fabsf(poly[0]) + fabsf(poly[1]) + fabsf(poly[2]) + fabsf(poly[3]);
  if (tid < DIM){
    work[tid] = make_float2(accs[tid].x/psum, accs[tid].y/psum);
  }
  __syncthreads();

  if (w == 0){
    float2 v[4];
    float ss = 0.f;
    #pragma unroll
    for (int r = 0; r < 4; ++r){
      float2 m = work[(r<<6) | lane];
      v[r] = m; ss += m.x*m.x + m.y*m.y;
    }
    ss = wave_sum(ss);
    float fp = sqrtf(ss);
    if (lane == 0) fprobs[b] = fp;
    float inv = 1.f / fmaxf(fp, 1e-12f);
    #pragma unroll
    for (int r = 0; r < 4; ++r){ v[r].x *= inv; v[r].y *= inv; }
    sim32(v, lane, (const float2*)qcs); // single layer, shared params
    measure_xyz(v, lane, exps);
  }
  __syncthreads();

  if (tid < EMBN){
    float a = ff1b[tid];
    const float* wr = ff1W + tid*24;
    #pragma unroll
    for (int m2 = 0; m2 < 24; ++m2) a += exps[m2]*wr[m2];
    a = fmaxf(a, 0.f);
    hT[tid*NB + b] = a;   // k-major layout hT[k][b] for uniform loads in k_out
  }
}

// ---------- K3: op = h @ ff2_W.T + ff2_b ; plus mean(final_probs) ----------
__global__ __launch_bounds__(256) void k_out(
    const float* __restrict__ hT, const float* __restrict__ ff2W,
    const float* __restrict__ ff2b, const float* __restrict__ fprobs,
    float* __restrict__ out)
{
  const int v = blockIdx.x*256 + threadIdx.x;
  if (blockIdx.x == 0 && threadIdx.x == 0){
    float s = 0.f;
    #pragma unroll
    for (int i = 0; i < 16; ++i) s += fprobs[i];
    out[(size_t)NB*VOCABN] = s * (1.f/16.f);
  }
  if (v >= VOCABN) return;
  const float4* wr = (const float4*)(ff2W + (size_t)v * EMBN);
  float acc[16];
  #pragma unroll
  for (int i = 0; i < 16; ++i) acc[i] = 0.f;
  for (int kc = 0; kc < EMBN/4; ++kc){
    float4 w4 = wr[kc];
    const float* hk = hT + kc*64;   // wave-uniform address -> scalar loads
    #pragma unroll
    for (int i = 0; i < 16; ++i)
      acc[i] += w4.x*hk[i] + w4.y*hk[16+i] + w4.z*hk[32+i] + w4.w*hk[48+i];
  }
  float bias = ff2b[v];
  #pragma unroll
  for (int i = 0; i < 16; ++i) out[(size_t)i*VOCABN + v] = acc[i] + bias;
}

extern "C" void kernel_launch(void* const* d_in, const int* in_sizes, int n_in,
                              void* d_out, int out_size, void* d_ws, size_t ws_size,
                              hipStream_t stream)
{
  const int*   x     = (const int*)  d_in[0];
  const float* embW  = (const float*)d_in[1];
  const float* e2rW  = (const float*)d_in[2];
  const float* e2rb  = (const float*)d_in[3];
  const float* poly  = (const float*)d_in[4];
  const float* mixri = (const float*)d_in[5];
  const float* qff   = (const float*)d_in[6];
  const float* ff1W  = (const float*)d_in[7];
  const float* ff1b  = (const float*)d_in[8];
  const float* ff2W  = (const float*)d_in[9];
  const float* ff2b  = (const float*)d_in[10];
  float* out = (float*)d_out;
  float* ws  = (float*)d_ws;

  float* wcs    = ws;            // 256*64*2 = 32768 floats
  float* coeffs = ws + 32768;    // 32 floats
  float* qcs    = ws + 32800;    // 64 floats
  float* hT     = ws + 32864;    // 512*16 = 8192 floats
  float* fprobs = ws + 41056;    // 16 floats

  k_prep<<<256, 64, 0, stream>>>(x, embW, e2rW, e2rb, mixri, qff, wcs, coeffs, qcs);
  k_sim <<<NB, 1024, 0, stream>>>(wcs, coeffs, qcs, poly, ff1W, ff1b, hT, fprobs);
  k_out <<<(VOCABN + 255)/256, 256, 0, stream>>>(hT, ff2W, ff2b, fprobs, out);
}